// Round 17
// baseline (117.028 us; speedup 1.0000x reference)
//
#include <hip/hip_runtime.h>
#include <math.h>

#define B 8
#define N 2048
#define F 1024
#define Z 256
#define K 10
#define OUT 2
#define EPSV 1e-5f
#define CCH 64            // cl chunks per bag
#define CHN (N / CCH)     // 32 instances per chunk
#define IPB5 32           // instances per inst5 block

typedef __attribute__((ext_vector_type(8))) short bf16x8;
typedef __attribute__((ext_vector_type(8))) unsigned short u16x8;
typedef __attribute__((ext_vector_type(4))) float f32x4;

__device__ __forceinline__ float fast_tanh(float x) {
    float t = __expf(2.0f * x);
    return 1.0f - 2.0f / (t + 1.0f);
}
__device__ __forceinline__ unsigned short f2bf_rne(float x) {
    unsigned int u = __float_as_uint(x);
    unsigned int r = (u + 0x7FFFu + ((u >> 16) & 1u)) >> 16;
    return (unsigned short)r;
}
__device__ __forceinline__ float bf2f(unsigned short h) {
    return __uint_as_float(((unsigned int)h) << 16);
}
__device__ __forceinline__ unsigned int pack2(unsigned short a, unsigned short b) {
    return (unsigned)a | ((unsigned)b << 16);
}

__device__ __forceinline__ float wave_sum(float v) {
    #pragma unroll
    for (int off = 32; off > 0; off >>= 1) v += __shfl_xor(v, off, 64);
    return v;
}
__device__ __forceinline__ float block_sum(float v, float* red) {
    int lane = threadIdx.x & 63, wave = threadIdx.x >> 6;
    v = wave_sum(v);
    __syncthreads();
    if (lane == 0) red[wave] = v;
    __syncthreads();
    return red[0] + red[1] + red[2] + red[3];
}

// ---- presplit: enc_W -> BtE [256][F] bf16 (BK=64 XOR swizzle);
//      ia_W1  -> W1T [256][256] bf16 plain transpose (for direct global reads).
__global__ __launch_bounds__(256)
void presplit2_kernel(const float* __restrict__ We, unsigned short* __restrict__ BtE,
                      const float* __restrict__ Wi, unsigned short* __restrict__ W1T)
{
    int tt = blockIdx.x * 256 + threadIdx.x;
    if (tt < F * 256) {
        int c = tt & 255;
        int k = tt >> 8;
        unsigned short h = f2bf_rne(We[(size_t)k * 256 + c]);
        int seg = k & ~63;
        int g = (k >> 3) & 7;
        int gs = g ^ (c & 7);
        BtE[(size_t)c * F + seg + gs * 8 + (k & 7)] = h;
    } else {
        int idx = tt - F * 256;
        int c = idx & 255;        // output dim d
        int k = idx >> 8;         // input dim z
        W1T[(size_t)c * Z + k] = f2bf_rne(Wi[(size_t)k * 256 + c]);
    }
}

// ---- gemm5 (r13 exact): 64x64 tile, 4 waves, acc[2][2], BK=64, dbuf, 2-phase ----
template<int EPI>
__global__ __launch_bounds__(256, 4)
void gemm5_kernel(const float* __restrict__ Af,
                  const unsigned short* __restrict__ Bt,
                  unsigned short* __restrict__ Cout, int Kd,
                  const float* __restrict__ bias,
                  const float* __restrict__ gamma, const float* __restrict__ beta,
                  const float* __restrict__ mean, const float* __restrict__ var)
{
    const int Nd = 256;
    __shared__ unsigned short A_s[2][64 * 64];   // 16 KB
    __shared__ unsigned short B_s[2][64 * 64];   // 16 KB

    int t = threadIdx.x;
    int l = t & 63, w = t >> 6;
    int wr = w >> 1, wc = w & 1;
    int lr = l & 15, lq = l >> 4;

    int nwg = gridDim.x;
    int bid = blockIdx.x;
    int lwg = (bid & 7) * (nwg >> 3) + (bid >> 3);
    int m0 = (lwg >> 2) * 64;
    int cb = (lwg & 3) * 64;

    int arow = t >> 2, aq = t & 3;

    f32x4 acc[2][2];
    #pragma unroll
    for (int i = 0; i < 2; ++i)
        #pragma unroll
        for (int j = 0; j < 2; ++j) acc[i][j] = (f32x4)0.0f;

    float4 areg[4];

    auto stageB = [&](int k0, int buf) {
        #pragma unroll
        for (int i = 0; i < 2; ++i) {
            int c0 = i * 256 + w * 64;
            int cc = c0 + l;
            int row = cc >> 3, gr = cc & 7;
            size_t src = (size_t)(cb + row) * Kd + k0 + gr * 8;
            __builtin_amdgcn_global_load_lds(
                (const __attribute__((address_space(1))) void*)(Bt + src),
                (__attribute__((address_space(3))) void*)((char*)&B_s[buf][0] + (size_t)cc * 16),
                16, 0, 0);
        }
    };
    auto loadA = [&](int k0) {
        #pragma unroll
        for (int q = 0; q < 4; ++q)
            areg[q] = *(const float4*)&Af[(size_t)(m0 + arow) * Kd + k0 + aq * 16 + q * 4];
    };
    auto writeA = [&](int buf) {
        #pragma unroll
        for (int j = 0; j < 2; ++j) {
            int g = aq * 2 + j;
            float4 v0 = areg[2 * j], v1 = areg[2 * j + 1];
            uint4 hv;
            hv.x = pack2(f2bf_rne(v0.x), f2bf_rne(v0.y));
            hv.y = pack2(f2bf_rne(v0.z), f2bf_rne(v0.w));
            hv.z = pack2(f2bf_rne(v1.x), f2bf_rne(v1.y));
            hv.w = pack2(f2bf_rne(v1.z), f2bf_rne(v1.w));
            *(uint4*)((char*)&A_s[buf][0] + arow * 128 + ((g ^ (arow & 7)) << 4)) = hv;
        }
    };

    int NK = Kd >> 6;
    loadA(0);
    stageB(0, 0);
    writeA(0);
    asm volatile("s_waitcnt vmcnt(0) lgkmcnt(0)" ::: "memory");
    __builtin_amdgcn_s_barrier();

    int cur = 0;
    for (int ks = 0; ks < NK; ++ks) {
        if (ks + 1 < NK) {
            int kn = (ks + 1) << 6;
            loadA(kn);
            stageB(kn, cur ^ 1);
        }
        #pragma unroll
        for (int sub = 0; sub < 2; ++sub) {
            int g = sub * 4 + lq;
            bf16x8 ah[2], bh[2];
            #pragma unroll
            for (int f = 0; f < 2; ++f) {
                int ra = wr * 32 + f * 16 + lr;
                ah[f] = *(const bf16x8*)((const char*)&A_s[cur][0] + ra * 128 + ((g ^ (ra & 7)) << 4));
                int rb = wc * 32 + f * 16 + lr;
                bh[f] = *(const bf16x8*)((const char*)&B_s[cur][0] + rb * 128 + ((g ^ (rb & 7)) << 4));
            }
            #pragma unroll
            for (int mi = 0; mi < 2; ++mi)
                #pragma unroll
                for (int ni = 0; ni < 2; ++ni)
                    acc[mi][ni] = __builtin_amdgcn_mfma_f32_16x16x32_bf16(
                        ah[mi], bh[ni], acc[mi][ni], 0, 0, 0);
        }
        if (ks + 1 < NK) {
            writeA(cur ^ 1);
            asm volatile("s_waitcnt vmcnt(0) lgkmcnt(0)" ::: "memory");
            __builtin_amdgcn_s_barrier();
        }
        cur ^= 1;
    }

    #pragma unroll
    for (int ni = 0; ni < 2; ++ni) {
        int c = cb + wc * 32 + ni * 16 + lr;
        float bi = 0.f, sc = 1.f, sh = 0.f;
        if (EPI == 1) {
            bi = bias[c];
            float rs = rsqrtf(var[c] + EPSV) * gamma[c];
            sc = rs;
            sh = beta[c] - mean[c] * rs;
        }
        #pragma unroll
        for (int mi = 0; mi < 2; ++mi) {
            int rbase = m0 + wr * 32 + mi * 16 + lq * 4;
            #pragma unroll
            for (int j = 0; j < 4; ++j) {
                float x = acc[mi][ni][j];
                if (EPI == 1) {
                    x = fmaxf(x + bi, 0.0f);
                    x = x * sc + sh;
                }
                Cout[(size_t)(rbase + j) * Nd + c] = f2bf_rne(x);
            }
        }
    }
}

// ---- inst5: 32 instances/block, 320 thr (5 waves). Fuses the g-GEMM:
// dist+softmax (thread=(i,k)) -> g = emb @ W1 via MFMA (waves 0..3, B from
// global W1T) -> tanh scores. g kept in fp32 LDS (more accurate than bf16).
__global__ __launch_bounds__(320)
void inst5_kernel(const unsigned short* __restrict__ emb16,
                  const unsigned short* __restrict__ W1T,
                  const float* __restrict__ cent, const float* __restrict__ ia_b1,
                  const float* __restrict__ ia_w2, const float* __restrict__ ia_b2,
                  float* __restrict__ soft_t, float* __restrict__ s_t)
{
    __shared__ unsigned short eS[IPB5][264];   // 16,896 B (528B rows, 16B-aligned)
    __shared__ float gS[IPB5][260];            // 33,280 B (1040B rows, 16B-aligned)
    __shared__ float cent_s[K][260];           // 10,400 B
    __shared__ float cn_s[K];
    __shared__ float b1_s[Z], w2_s[Z];         // 2,048 B
    __shared__ float nd_s[IPB5][10];           // 1,280 B

    int t = threadIdx.x;
    int i = t / 10;                  // instance 0..31
    int k = t - i * 10;              // cluster 0..9
    int inst0 = blockIdx.x * IPB5;
    int b = inst0 >> 11;             // / N
    int n0 = inst0 & (N - 1);

    // ---- stage cent (padded), b1, w2, emb ----
    for (int idx = t; idx < (K * Z) / 4; idx += 320) {
        int row = idx >> 6, c4 = idx & 63;
        *(float4*)&cent_s[row][c4 * 4] = ((const float4*)cent)[idx];
    }
    if (t < Z) { b1_s[t] = ia_b1[t]; w2_s[t] = ia_w2[t]; }
    for (int idx = t; idx < IPB5 * 32; idx += 320) {
        int rr = idx >> 5, c = idx & 31;
        *(u16x8*)&eS[rr][c * 8] = *(const u16x8*)&emb16[(size_t)(inst0 + rr) * Z + c * 8];
    }
    __syncthreads();

    if (t < K) {
        float s = 0.0f;
        for (int z = 0; z < Z; ++z) s += cent_s[t][z] * cent_s[t][z];
        cn_s[t] = s;
    }
    __syncthreads();

    // ---- phase 1: dist per (i,k) over full z ----
    {
        float dot = 0.0f, en2 = 0.0f;
        #pragma unroll 4
        for (int zc = 0; zc < 32; ++zc) {
            int z8 = zc * 8;
            u16x8 e8 = *(const u16x8*)&eS[i][z8];
            float4 ca = *(const float4*)&cent_s[k][z8];
            float4 cbv = *(const float4*)&cent_s[k][z8 + 4];
            float ev[8];
            #pragma unroll
            for (int j = 0; j < 8; ++j) ev[j] = bf2f((unsigned short)e8[j]);
            dot = fmaf(ev[0], ca.x, dot);  dot = fmaf(ev[1], ca.y, dot);
            dot = fmaf(ev[2], ca.z, dot);  dot = fmaf(ev[3], ca.w, dot);
            dot = fmaf(ev[4], cbv.x, dot); dot = fmaf(ev[5], cbv.y, dot);
            dot = fmaf(ev[6], cbv.z, dot); dot = fmaf(ev[7], cbv.w, dot);
            #pragma unroll
            for (int j = 0; j < 8; ++j) en2 = fmaf(ev[j], ev[j], en2);
        }
        float d2 = en2 + cn_s[k] - 2.0f * dot;
        nd_s[i][k] = -sqrtf(fmaxf(d2, 0.0f));
    }
    __syncthreads();

    // ---- per-thread softmax over the instance's K values ----
    float mx = nd_s[i][0];
    #pragma unroll
    for (int kk = 1; kk < K; ++kk) mx = fmaxf(mx, nd_s[i][kk]);
    float se = 0.0f;
    #pragma unroll
    for (int kk = 0; kk < K; ++kk) se += __expf(nd_s[i][kk] - mx);
    float sm = __expf(nd_s[i][k] - mx) / se;
    soft_t[((size_t)b * K + k) * N + n0 + i] = sm;

    // ---- phase 2: g = emb @ W1 via MFMA (waves 0..3; wave = 64 output cols) ----
    int w = t >> 6, l = t & 63, lr = l & 15, lq = l >> 4;
    f32x4 acc[2][4];
    #pragma unroll
    for (int mt = 0; mt < 2; ++mt)
        #pragma unroll
        for (int ct = 0; ct < 4; ++ct) acc[mt][ct] = (f32x4)0.0f;
    if (w < 4) {
        #pragma unroll
        for (int ks = 0; ks < 8; ++ks) {
            bf16x8 ah[2], bh[4];
            #pragma unroll
            for (int mt = 0; mt < 2; ++mt)
                ah[mt] = *(const bf16x8*)&eS[mt * 16 + lr][ks * 32 + lq * 8];
            #pragma unroll
            for (int ct = 0; ct < 4; ++ct) {
                int col = w * 64 + ct * 16 + lr;
                bh[ct] = *(const bf16x8*)&W1T[(size_t)col * Z + ks * 32 + lq * 8];
            }
            #pragma unroll
            for (int mt = 0; mt < 2; ++mt)
                #pragma unroll
                for (int ct = 0; ct < 4; ++ct)
                    acc[mt][ct] = __builtin_amdgcn_mfma_f32_16x16x32_bf16(
                        ah[mt], bh[ct], acc[mt][ct], 0, 0, 0);
        }
        #pragma unroll
        for (int mt = 0; mt < 2; ++mt)
            #pragma unroll
            for (int ct = 0; ct < 4; ++ct)
                #pragma unroll
                for (int j = 0; j < 4; ++j)
                    gS[mt * 16 + lq * 4 + j][w * 64 + ct * 16 + lr] = acc[mt][ct][j];
    }
    __syncthreads();

    // ---- phase 3: s = sum_z w2[z] * tanh(sm * g[z] + b1[z]) ----
    {
        float a2 = 0.0f;
        #pragma unroll 2
        for (int zc = 0; zc < 32; ++zc) {
            int z8 = zc * 8;
            float4 ga = *(const float4*)&gS[i][z8];
            float4 gb = *(const float4*)&gS[i][z8 + 4];
            float4 b1a = *(const float4*)&b1_s[z8];
            float4 b1b = *(const float4*)&b1_s[z8 + 4];
            float4 w2a = *(const float4*)&w2_s[z8];
            float4 w2b = *(const float4*)&w2_s[z8 + 4];
            a2 = fmaf(w2a.x, fast_tanh(fmaf(sm, ga.x, b1a.x)), a2);
            a2 = fmaf(w2a.y, fast_tanh(fmaf(sm, ga.y, b1a.y)), a2);
            a2 = fmaf(w2a.z, fast_tanh(fmaf(sm, ga.z, b1a.z)), a2);
            a2 = fmaf(w2a.w, fast_tanh(fmaf(sm, ga.w, b1a.w)), a2);
            a2 = fmaf(w2b.x, fast_tanh(fmaf(sm, gb.x, b1b.x)), a2);
            a2 = fmaf(w2b.y, fast_tanh(fmaf(sm, gb.y, b1b.y)), a2);
            a2 = fmaf(w2b.z, fast_tanh(fmaf(sm, gb.z, b1b.z)), a2);
            a2 = fmaf(w2b.w, fast_tanh(fmaf(sm, gb.w, b1b.w)), a2);
        }
        s_t[((size_t)b * K + k) * N + n0 + i] = a2 + ia_b2[0];
    }
}

__global__ __launch_bounds__(256)
void attn_kernel(const float* __restrict__ s_t, const float* __restrict__ soft_t,
                 float* __restrict__ as_t)
{
    __shared__ float red[4];
    __shared__ float redm[4];
    int bk = blockIdx.x;
    int t = threadIdx.x;
    int lane = t & 63, wave = t >> 6;
    const float* s = &s_t[(size_t)bk * N];
    float v[8];
    float mx = -1e30f;
    #pragma unroll
    for (int i = 0; i < 8; ++i) { v[i] = s[t + i * 256]; mx = fmaxf(mx, v[i]); }
    #pragma unroll
    for (int off = 32; off > 0; off >>= 1) mx = fmaxf(mx, __shfl_xor(mx, off, 64));
    if (lane == 0) redm[wave] = mx;
    __syncthreads();
    mx = fmaxf(fmaxf(redm[0], redm[1]), fmaxf(redm[2], redm[3]));
    float se = 0.0f;
    #pragma unroll
    for (int i = 0; i < 8; ++i) { v[i] = __expf(v[i] - mx); se += v[i]; }
    se = block_sum(se, red);
    float inv = 1.0f / se;
    const float* so = &soft_t[(size_t)bk * N];
    float* as = &as_t[(size_t)bk * N];
    #pragma unroll
    for (int i = 0; i < 8; ++i) as[t + i * 256] = v[i] * inv * so[t + i * 256];
}

__global__ __launch_bounds__(256)
void cl_part_kernel(const float* __restrict__ as_t, const unsigned short* __restrict__ emb16,
                    float* __restrict__ part)
{
    __shared__ float sas[K][CHN];
    int b = blockIdx.x / CCH, c = blockIdx.x % CCH;
    int z = threadIdx.x;
    int n0 = c * CHN;
    for (int i = threadIdx.x; i < K * CHN; i += 256) {
        int k = i / CHN, n = i % CHN;
        sas[k][n] = as_t[((size_t)b * K + k) * N + n0 + n];
    }
    __syncthreads();
    float acc[K] = {};
    #pragma unroll 4
    for (int j = 0; j < CHN; ++j) {
        float e = bf2f(emb16[((size_t)b * N + n0 + j) * Z + z]);
        #pragma unroll
        for (int k = 0; k < K; ++k) acc[k] = fmaf(sas[k][j], e, acc[k]);
    }
    #pragma unroll
    for (int k = 0; k < K; ++k)
        part[(((size_t)b * CCH + c) * K + k) * Z + z] = acc[k];
}

// ---- fused: cl reduce over chunks + cluster-attention score sck[b,k] ----
__global__ __launch_bounds__(256)
void clred_sck_kernel(const float* __restrict__ part, float* __restrict__ cl,
                      const float* __restrict__ ca_W1, const float* __restrict__ ca_b1,
                      const float* __restrict__ ca_w2, const float* __restrict__ ca_b2,
                      float* __restrict__ sck)
{
    __shared__ float scl[Z];
    __shared__ float red[4];
    int bk = blockIdx.x;
    int b = bk / K, k = bk % K;
    int t = threadIdx.x;
    float s = 0.0f;
    #pragma unroll 8
    for (int c = 0; c < CCH; ++c)
        s += part[(((size_t)b * CCH + c) * K + k) * Z + t];
    cl[(size_t)bk * Z + t] = s;
    scl[t] = s;
    __syncthreads();
    float acc = 0.0f;
    #pragma unroll 8
    for (int z = 0; z < Z; ++z)
        acc = fmaf(scl[z], ca_W1[(size_t)z * Z + t], acc);
    float h = fast_tanh(acc + ca_b1[t]);
    float v = block_sum(h * ca_w2[t], red);
    if (t == 0) sck[bk] = v + ca_b2[0];
}

__global__ __launch_bounds__(256)
void head_fin_kernel(const float* __restrict__ cl, const float* __restrict__ sck,
                     const float* __restrict__ hg, const float* __restrict__ hb,
                     const float* __restrict__ hm, const float* __restrict__ hv,
                     const float* __restrict__ head_W, const float* __restrict__ head_b,
                     float* __restrict__ outp)
{
    __shared__ float red[4];
    __shared__ float sks[K];
    int b = blockIdx.x, t = threadIdx.x;
    if (t < K) sks[t] = sck[b * K + t];
    __syncthreads();
    float mx = sks[0];
    #pragma unroll
    for (int k = 1; k < K; ++k) mx = fmaxf(mx, sks[k]);
    float e[K], se = 0.0f;
    #pragma unroll
    for (int k = 0; k < K; ++k) { e[k] = __expf(sks[k] - mx); se += e[k]; }
    float inv = 1.0f / se;
    float pooled = 0.0f;
    #pragma unroll
    for (int k = 0; k < K; ++k)
        pooled = fmaf(e[k] * inv, cl[((size_t)b * K + k) * Z + t], pooled);
    pooled = (pooled - hm[t]) * rsqrtf(hv[t] + EPSV) * hg[t] + hb[t];
    float p0 = block_sum(pooled * head_W[t * OUT + 0], red);
    __syncthreads();
    float p1 = block_sum(pooled * head_W[t * OUT + 1], red);
    if (t == 0) {
        outp[b * OUT + 0] = p0 + head_b[0];
        outp[b * OUT + 1] = p1 + head_b[1];
    }
}

extern "C" void kernel_launch(void* const* d_in, const int* in_sizes, int n_in,
                              void* d_out, int out_size, void* d_ws, size_t ws_size,
                              hipStream_t stream)
{
    const float* bags      = (const float*)d_in[0];
    const float* enc_W     = (const float*)d_in[1];
    const float* enc_b     = (const float*)d_in[2];
    const float* bn1_gamma = (const float*)d_in[3];
    const float* bn1_beta  = (const float*)d_in[4];
    const float* bn1_mean  = (const float*)d_in[5];
    const float* bn1_var   = (const float*)d_in[6];
    const float* centroids = (const float*)d_in[7];
    const float* ia_W1     = (const float*)d_in[8];
    const float* ia_b1     = (const float*)d_in[9];
    const float* ia_w2     = (const float*)d_in[10];
    const float* ia_b2     = (const float*)d_in[11];
    const float* ca_W1     = (const float*)d_in[12];
    const float* ca_b1     = (const float*)d_in[13];
    const float* ca_w2     = (const float*)d_in[14];
    const float* ca_b2     = (const float*)d_in[15];
    const float* hg        = (const float*)d_in[16];
    const float* hb        = (const float*)d_in[17];
    const float* hm        = (const float*)d_in[18];
    const float* hv        = (const float*)d_in[19];
    const float* head_W    = (const float*)d_in[20];
    const float* head_b    = (const float*)d_in[21];

    char* ws = (char*)d_ws;
    unsigned short* emb16 = (unsigned short*)ws;                       // 8 MB
    float* part  = (float*)(ws + ((size_t)8 << 20));                   // 5.25 MB
    unsigned short* BtE   = (unsigned short*)(ws + ((size_t)16 << 20));          // 512 KB
    unsigned short* W1T   = (unsigned short*)(ws + ((size_t)17 << 20));          // 128 KB
    float* soft_t = (float*)(ws + ((size_t)18 << 20));                 // [B,K,N]
    float* s_t    = soft_t + (size_t)B * K * N;
    float* as_t   = s_t    + (size_t)B * K * N;
    float* cl     = as_t   + (size_t)B * K * N;
    float* sck    = cl     + (size_t)B * K * Z;

    presplit2_kernel<<<((F + Z) * 256) / 256, 256, 0, stream>>>(enc_W, BtE, ia_W1, W1T);

    int nblk = ((B * N) / 64) * (Z / 64);   // 1024
    gemm5_kernel<1><<<nblk, 256, 0, stream>>>(bags, BtE, emb16, F,
                                              enc_b, bn1_gamma, bn1_beta, bn1_mean, bn1_var);

    inst5_kernel<<<(B * N) / IPB5, 320, 0, stream>>>(emb16, W1T, centroids,
                                                     ia_b1, ia_w2, ia_b2, soft_t, s_t);
    attn_kernel<<<B * K, 256, 0, stream>>>(s_t, soft_t, as_t);
    cl_part_kernel<<<B * CCH, 256, 0, stream>>>(as_t, emb16, part);
    clred_sck_kernel<<<B * K, 256, 0, stream>>>(part, cl, ca_W1, ca_b1, ca_w2, ca_b2, sck);
    head_fin_kernel<<<B, 256, 0, stream>>>(cl, sck, hg, hb, hm, hv, head_W, head_b,
                                           (float*)d_out);
}

// Round 20
// 110.280 us; speedup vs baseline: 1.0612x; 1.0612x over previous
//
#include <hip/hip_runtime.h>
#include <math.h>

#define B 8
#define N 2048
#define F 1024
#define Z 256
#define K 10
#define OUT 2
#define EPSV 1e-5f
#define CCH 64            // cl chunks per bag
#define CHN (N / CCH)     // 32 instances per chunk
#define IPB4 16           // instances per inst4 block

typedef __attribute__((ext_vector_type(8))) short bf16x8;
typedef __attribute__((ext_vector_type(8))) unsigned short u16x8;
typedef __attribute__((ext_vector_type(4))) float f32x4;

__device__ __forceinline__ float fast_tanh(float x) {
    float t = __expf(2.0f * x);
    return 1.0f - 2.0f / (t + 1.0f);
}
__device__ __forceinline__ unsigned short f2bf_rne(float x) {
    unsigned int u = __float_as_uint(x);
    unsigned int r = (u + 0x7FFFu + ((u >> 16) & 1u)) >> 16;
    return (unsigned short)r;
}
__device__ __forceinline__ float bf2f(unsigned short h) {
    return __uint_as_float(((unsigned int)h) << 16);
}
__device__ __forceinline__ unsigned int pack2(unsigned short a, unsigned short b) {
    return (unsigned)a | ((unsigned)b << 16);
}

__device__ __forceinline__ float wave_sum(float v) {
    #pragma unroll
    for (int off = 32; off > 0; off >>= 1) v += __shfl_xor(v, off, 64);
    return v;
}
__device__ __forceinline__ float block_sum(float v, float* red) {
    int lane = threadIdx.x & 63, wave = threadIdx.x >> 6;
    v = wave_sum(v);
    __syncthreads();
    if (lane == 0) red[wave] = v;
    __syncthreads();
    return red[0] + red[1] + red[2] + red[3];
}

// ---- presplit both weights: W [Kd][256] fp32 -> Bt [256][Kd] bf16 (XOR swz) ----
__global__ __launch_bounds__(256)
void presplit2_kernel(const float* __restrict__ We, unsigned short* __restrict__ BtE,
                      const float* __restrict__ Wi, unsigned short* __restrict__ BtI)
{
    int tt = blockIdx.x * 256 + threadIdx.x;
    const float* W;
    unsigned short* Bt;
    int Kd, idx;
    if (tt < F * 256) { W = We; Bt = BtE; Kd = F; idx = tt; }
    else              { W = Wi; Bt = BtI; Kd = Z; idx = tt - F * 256; }
    int c = idx & 255;
    int k = idx >> 8;
    unsigned short h = f2bf_rne(W[(size_t)k * 256 + c]);
    int seg = k & ~63;
    int g = (k >> 3) & 7;
    int gs = g ^ (c & 7);
    Bt[(size_t)c * Kd + seg + gs * 8 + (k & 7)] = h;
}

// ---- gemm5 (r13 exact): 64x64 tile, 4 waves, acc[2][2], BK=64, dbuf, 2-phase ----
template<int EPI, int ABF16>
__global__ __launch_bounds__(256, 4)
void gemm5_kernel(const void* __restrict__ Ap,
                  const unsigned short* __restrict__ Bt,
                  unsigned short* __restrict__ Cout, int Kd,
                  const float* __restrict__ bias,
                  const float* __restrict__ gamma, const float* __restrict__ beta,
                  const float* __restrict__ mean, const float* __restrict__ var)
{
    const int Nd = 256;
    __shared__ unsigned short A_s[2][64 * 64];   // 16 KB
    __shared__ unsigned short B_s[2][64 * 64];   // 16 KB

    int t = threadIdx.x;
    int l = t & 63, w = t >> 6;
    int wr = w >> 1, wc = w & 1;
    int lr = l & 15, lq = l >> 4;

    int nwg = gridDim.x;
    int bid = blockIdx.x;
    int lwg = (bid & 7) * (nwg >> 3) + (bid >> 3);
    int m0 = (lwg >> 2) * 64;
    int cb = (lwg & 3) * 64;

    int arow = t >> 2, aq = t & 3;

    f32x4 acc[2][2];
    #pragma unroll
    for (int i = 0; i < 2; ++i)
        #pragma unroll
        for (int j = 0; j < 2; ++j) acc[i][j] = (f32x4)0.0f;

    const float* Af = (const float*)Ap;
    const unsigned short* Ab = (const unsigned short*)Ap;
    float4 areg[4];

    auto stageB = [&](int k0, int buf) {
        #pragma unroll
        for (int i = 0; i < 2; ++i) {
            int c0 = i * 256 + w * 64;
            int cc = c0 + l;
            int row = cc >> 3, gr = cc & 7;
            size_t src = (size_t)(cb + row) * Kd + k0 + gr * 8;
            __builtin_amdgcn_global_load_lds(
                (const __attribute__((address_space(1))) void*)(Bt + src),
                (__attribute__((address_space(3))) void*)((char*)&B_s[buf][0] + (size_t)cc * 16),
                16, 0, 0);
        }
    };
    auto stageA16 = [&](int k0, int buf) {
        #pragma unroll
        for (int i = 0; i < 2; ++i) {
            int c0 = i * 256 + w * 64;
            int cc = c0 + l;
            int row = cc >> 3, gr = cc & 7;
            size_t src = (size_t)(m0 + row) * Kd + k0 + ((gr ^ (row & 7)) << 3);
            __builtin_amdgcn_global_load_lds(
                (const __attribute__((address_space(1))) void*)(Ab + src),
                (__attribute__((address_space(3))) void*)((char*)&A_s[buf][0] + (size_t)cc * 16),
                16, 0, 0);
        }
    };
    auto loadA = [&](int k0) {
        #pragma unroll
        for (int q = 0; q < 4; ++q)
            areg[q] = *(const float4*)&Af[(size_t)(m0 + arow) * Kd + k0 + aq * 16 + q * 4];
    };
    auto writeA = [&](int buf) {
        #pragma unroll
        for (int j = 0; j < 2; ++j) {
            int g = aq * 2 + j;
            float4 v0 = areg[2 * j], v1 = areg[2 * j + 1];
            uint4 hv;
            hv.x = pack2(f2bf_rne(v0.x), f2bf_rne(v0.y));
            hv.y = pack2(f2bf_rne(v0.z), f2bf_rne(v0.w));
            hv.z = pack2(f2bf_rne(v1.x), f2bf_rne(v1.y));
            hv.w = pack2(f2bf_rne(v1.z), f2bf_rne(v1.w));
            *(uint4*)((char*)&A_s[buf][0] + arow * 128 + ((g ^ (arow & 7)) << 4)) = hv;
        }
    };

    int NK = Kd >> 6;
    if (ABF16) stageA16(0, 0);
    else       loadA(0);
    stageB(0, 0);
    if (!ABF16) writeA(0);
    asm volatile("s_waitcnt vmcnt(0) lgkmcnt(0)" ::: "memory");
    __builtin_amdgcn_s_barrier();

    int cur = 0;
    for (int ks = 0; ks < NK; ++ks) {
        if (ks + 1 < NK) {
            int kn = (ks + 1) << 6;
            if (ABF16) stageA16(kn, cur ^ 1);
            else       loadA(kn);
            stageB(kn, cur ^ 1);
        }
        #pragma unroll
        for (int sub = 0; sub < 2; ++sub) {
            int g = sub * 4 + lq;
            bf16x8 ah[2], bh[2];
            #pragma unroll
            for (int f = 0; f < 2; ++f) {
                int ra = wr * 32 + f * 16 + lr;
                ah[f] = *(const bf16x8*)((const char*)&A_s[cur][0] + ra * 128 + ((g ^ (ra & 7)) << 4));
                int rb = wc * 32 + f * 16 + lr;
                bh[f] = *(const bf16x8*)((const char*)&B_s[cur][0] + rb * 128 + ((g ^ (rb & 7)) << 4));
            }
            #pragma unroll
            for (int mi = 0; mi < 2; ++mi)
                #pragma unroll
                for (int ni = 0; ni < 2; ++ni)
                    acc[mi][ni] = __builtin_amdgcn_mfma_f32_16x16x32_bf16(
                        ah[mi], bh[ni], acc[mi][ni], 0, 0, 0);
        }
        if (ks + 1 < NK) {
            if (!ABF16) writeA(cur ^ 1);
            asm volatile("s_waitcnt vmcnt(0) lgkmcnt(0)" ::: "memory");
            __builtin_amdgcn_s_barrier();
        }
        cur ^= 1;
    }

    #pragma unroll
    for (int ni = 0; ni < 2; ++ni) {
        int c = cb + wc * 32 + ni * 16 + lr;
        float bi = 0.f, sc = 1.f, sh = 0.f;
        if (EPI == 1) {
            bi = bias[c];
            float rs = rsqrtf(var[c] + EPSV) * gamma[c];
            sc = rs;
            sh = beta[c] - mean[c] * rs;
        }
        #pragma unroll
        for (int mi = 0; mi < 2; ++mi) {
            int rbase = m0 + wr * 32 + mi * 16 + lq * 4;
            #pragma unroll
            for (int j = 0; j < 4; ++j) {
                float x = acc[mi][ni][j];
                if (EPI == 1) {
                    x = fmaxf(x + bi, 0.0f);
                    x = x * sc + sh;
                }
                Cout[(size_t)(rbase + j) * Nd + c] = f2bf_rne(x);
            }
        }
    }
}

// ---- inst4 (r13 exact): thread = (instance, k, z-half). 320 thr / 16 inst. ----
__global__ __launch_bounds__(320)
void inst4_kernel(const unsigned short* __restrict__ emb16,
                  const unsigned short* __restrict__ g16,
                  const float* __restrict__ cent, const float* __restrict__ ia_b1,
                  const float* __restrict__ ia_w2, const float* __restrict__ ia_b2,
                  float* __restrict__ soft_t, float* __restrict__ s_t)
{
    __shared__ unsigned short eg[IPB4][280];
    __shared__ float cent_s[K][260];
    __shared__ float cn_s[K];
    __shared__ float b1_s[Z], w2_s[Z];
    __shared__ float part_d[IPB4][K][2];
    __shared__ float en2_s[IPB4][2];
    __shared__ float nd_s[IPB4][12];

    int t = threadIdx.x;
    int half = t / 160;
    int r = t - half * 160;
    int i = r / 10;
    int k = r - i * 10;
    int inst0 = blockIdx.x * IPB4;
    int b = inst0 >> 11;
    int n0 = inst0 & (N - 1);

    for (int idx = t; idx < (K * Z) / 4; idx += 320) {
        int row = idx >> 6, c4 = idx & 63;
        *(float4*)&cent_s[row][c4 * 4] = ((const float4*)cent)[idx];
    }
    if (t < Z) { b1_s[t] = ia_b1[t]; w2_s[t] = ia_w2[t]; }
    for (int idx = t; idx < IPB4 * 32; idx += 320) {
        int rr = idx >> 5, c = idx & 31;
        *(u16x8*)&eg[rr][c * 8] = *(const u16x8*)&emb16[(size_t)(inst0 + rr) * Z + c * 8];
    }
    __syncthreads();

    if (t < K) {
        float s = 0.0f;
        for (int z = 0; z < Z; ++z) s += cent_s[t][z] * cent_s[t][z];
        cn_s[t] = s;
    }
    __syncthreads();

    {
        float dot = 0.0f, en2 = 0.0f;
        int zb = half * 16;
        #pragma unroll 4
        for (int zc = 0; zc < 16; ++zc) {
            int z8 = (zb + zc) * 8;
            u16x8 e8 = *(const u16x8*)&eg[i][z8];
            float4 ca = *(const float4*)&cent_s[k][z8];
            float4 cbv = *(const float4*)&cent_s[k][z8 + 4];
            float ev[8];
            #pragma unroll
            for (int j = 0; j < 8; ++j) ev[j] = bf2f((unsigned short)e8[j]);
            dot = fmaf(ev[0], ca.x, dot);  dot = fmaf(ev[1], ca.y, dot);
            dot = fmaf(ev[2], ca.z, dot);  dot = fmaf(ev[3], ca.w, dot);
            dot = fmaf(ev[4], cbv.x, dot); dot = fmaf(ev[5], cbv.y, dot);
            dot = fmaf(ev[6], cbv.z, dot); dot = fmaf(ev[7], cbv.w, dot);
            #pragma unroll
            for (int j = 0; j < 8; ++j) en2 = fmaf(ev[j], ev[j], en2);
        }
        part_d[i][k][half] = dot;
        if (k == 0) en2_s[i][half] = en2;
    }
    __syncthreads();

    if (half == 0) {
        float dsum = part_d[i][k][0] + part_d[i][k][1];
        float e2 = en2_s[i][0] + en2_s[i][1];
        float d2 = e2 + cn_s[k] - 2.0f * dsum;
        nd_s[i][k] = -sqrtf(fmaxf(d2, 0.0f));
    }
    __syncthreads();

    float mx = nd_s[i][0];
    #pragma unroll
    for (int kk = 1; kk < K; ++kk) mx = fmaxf(mx, nd_s[i][kk]);
    float se = 0.0f;
    #pragma unroll
    for (int kk = 0; kk < K; ++kk) se += __expf(nd_s[i][kk] - mx);
    float sm = __expf(nd_s[i][k] - mx) / se;
    if (half == 0) soft_t[((size_t)b * K + k) * N + n0 + i] = sm;
    __syncthreads();

    for (int idx = t; idx < IPB4 * 32; idx += 320) {
        int rr = idx >> 5, c = idx & 31;
        *(u16x8*)&eg[rr][c * 8] = *(const u16x8*)&g16[(size_t)(inst0 + rr) * Z + c * 8];
    }
    __syncthreads();

    {
        float acc = 0.0f;
        int zb = half * 16;
        #pragma unroll 2
        for (int zc = 0; zc < 16; ++zc) {
            int z8 = (zb + zc) * 8;
            u16x8 g8 = *(const u16x8*)&eg[i][z8];
            float4 b1a = *(const float4*)&b1_s[z8];
            float4 b1b = *(const float4*)&b1_s[z8 + 4];
            float4 w2a = *(const float4*)&w2_s[z8];
            float4 w2b = *(const float4*)&w2_s[z8 + 4];
            float gv[8];
            #pragma unroll
            for (int j = 0; j < 8; ++j) gv[j] = bf2f((unsigned short)g8[j]);
            acc = fmaf(w2a.x, fast_tanh(fmaf(sm, gv[0], b1a.x)), acc);
            acc = fmaf(w2a.y, fast_tanh(fmaf(sm, gv[1], b1a.y)), acc);
            acc = fmaf(w2a.z, fast_tanh(fmaf(sm, gv[2], b1a.z)), acc);
            acc = fmaf(w2a.w, fast_tanh(fmaf(sm, gv[3], b1a.w)), acc);
            acc = fmaf(w2b.x, fast_tanh(fmaf(sm, gv[4], b1b.x)), acc);
            acc = fmaf(w2b.y, fast_tanh(fmaf(sm, gv[5], b1b.y)), acc);
            acc = fmaf(w2b.z, fast_tanh(fmaf(sm, gv[6], b1b.z)), acc);
            acc = fmaf(w2b.w, fast_tanh(fmaf(sm, gv[7], b1b.w)), acc);
        }
        part_d[i][k][half] = acc;
    }
    __syncthreads();

    if (half == 0) {
        float s = part_d[i][k][0] + part_d[i][k][1] + ia_b2[0];
        s_t[((size_t)b * K + k) * N + n0 + i] = s;
    }
}

__global__ __launch_bounds__(256)
void attn_kernel(const float* __restrict__ s_t, const float* __restrict__ soft_t,
                 float* __restrict__ as_t)
{
    __shared__ float red[4];
    __shared__ float redm[4];
    int bk = blockIdx.x;
    int t = threadIdx.x;
    int lane = t & 63, wave = t >> 6;
    const float* s = &s_t[(size_t)bk * N];
    float v[8];
    float mx = -1e30f;
    #pragma unroll
    for (int i = 0; i < 8; ++i) { v[i] = s[t + i * 256]; mx = fmaxf(mx, v[i]); }
    #pragma unroll
    for (int off = 32; off > 0; off >>= 1) mx = fmaxf(mx, __shfl_xor(mx, off, 64));
    if (lane == 0) redm[wave] = mx;
    __syncthreads();
    mx = fmaxf(fmaxf(redm[0], redm[1]), fmaxf(redm[2], redm[3]));
    float se = 0.0f;
    #pragma unroll
    for (int i = 0; i < 8; ++i) { v[i] = __expf(v[i] - mx); se += v[i]; }
    se = block_sum(se, red);
    float inv = 1.0f / se;
    const float* so = &soft_t[(size_t)bk * N];
    float* as = &as_t[(size_t)bk * N];
    #pragma unroll
    for (int i = 0; i < 8; ++i) as[t + i * 256] = v[i] * inv * so[t + i * 256];
}

__global__ __launch_bounds__(256)
void cl_part_kernel(const float* __restrict__ as_t, const unsigned short* __restrict__ emb16,
                    float* __restrict__ part)
{
    __shared__ float sas[K][CHN];
    int b = blockIdx.x / CCH, c = blockIdx.x % CCH;
    int z = threadIdx.x;
    int n0 = c * CHN;
    for (int i = threadIdx.x; i < K * CHN; i += 256) {
        int k = i / CHN, n = i % CHN;
        sas[k][n] = as_t[((size_t)b * K + k) * N + n0 + n];
    }
    __syncthreads();
    float acc[K] = {};
    #pragma unroll 4
    for (int j = 0; j < CHN; ++j) {
        float e = bf2f(emb16[((size_t)b * N + n0 + j) * Z + z]);
        #pragma unroll
        for (int k = 0; k < K; ++k) acc[k] = fmaf(sas[k][j], e, acc[k]);
    }
    #pragma unroll
    for (int k = 0; k < K; ++k)
        part[(((size_t)b * CCH + c) * K + k) * Z + z] = acc[k];
}

// ---- fused (r14-proven): cl reduce over chunks + cluster-attn score sck ----
__global__ __launch_bounds__(256)
void clred_sck_kernel(const float* __restrict__ part, float* __restrict__ cl,
                      const float* __restrict__ ca_W1, const float* __restrict__ ca_b1,
                      const float* __restrict__ ca_w2, const float* __restrict__ ca_b2,
                      float* __restrict__ sck)
{
    __shared__ float scl[Z];
    __shared__ float red[4];
    int bk = blockIdx.x;
    int b = bk / K, k = bk % K;
    int t = threadIdx.x;
    float s = 0.0f;
    #pragma unroll 8
    for (int c = 0; c < CCH; ++c)
        s += part[(((size_t)b * CCH + c) * K + k) * Z + t];
    cl[(size_t)bk * Z + t] = s;
    scl[t] = s;
    __syncthreads();
    float acc = 0.0f;
    #pragma unroll 8
    for (int z = 0; z < Z; ++z)
        acc = fmaf(scl[z], ca_W1[(size_t)z * Z + t], acc);
    float h = fast_tanh(acc + ca_b1[t]);
    float v = block_sum(h * ca_w2[t], red);
    if (t == 0) sck[bk] = v + ca_b2[0];
}

__global__ __launch_bounds__(256)
void head_fin_kernel(const float* __restrict__ cl, const float* __restrict__ sck,
                     const float* __restrict__ hg, const float* __restrict__ hb,
                     const float* __restrict__ hm, const float* __restrict__ hv,
                     const float* __restrict__ head_W, const float* __restrict__ head_b,
                     float* __restrict__ outp)
{
    __shared__ float red[4];
    __shared__ float sks[K];
    int b = blockIdx.x, t = threadIdx.x;
    if (t < K) sks[t] = sck[b * K + t];
    __syncthreads();
    float mx = sks[0];
    #pragma unroll
    for (int k = 1; k < K; ++k) mx = fmaxf(mx, sks[k]);
    float e[K], se = 0.0f;
    #pragma unroll
    for (int k = 0; k < K; ++k) { e[k] = __expf(sks[k] - mx); se += e[k]; }
    float inv = 1.0f / se;
    float pooled = 0.0f;
    #pragma unroll
    for (int k = 0; k < K; ++k)
        pooled = fmaf(e[k] * inv, cl[((size_t)b * K + k) * Z + t], pooled);
    pooled = (pooled - hm[t]) * rsqrtf(hv[t] + EPSV) * hg[t] + hb[t];
    float p0 = block_sum(pooled * head_W[t * OUT + 0], red);
    __syncthreads();
    float p1 = block_sum(pooled * head_W[t * OUT + 1], red);
    if (t == 0) {
        outp[b * OUT + 0] = p0 + head_b[0];
        outp[b * OUT + 1] = p1 + head_b[1];
    }
}

extern "C" void kernel_launch(void* const* d_in, const int* in_sizes, int n_in,
                              void* d_out, int out_size, void* d_ws, size_t ws_size,
                              hipStream_t stream)
{
    const float* bags      = (const float*)d_in[0];
    const float* enc_W     = (const float*)d_in[1];
    const float* enc_b     = (const float*)d_in[2];
    const float* bn1_gamma = (const float*)d_in[3];
    const float* bn1_beta  = (const float*)d_in[4];
    const float* bn1_mean  = (const float*)d_in[5];
    const float* bn1_var   = (const float*)d_in[6];
    const float* centroids = (const float*)d_in[7];
    const float* ia_W1     = (const float*)d_in[8];
    const float* ia_b1     = (const float*)d_in[9];
    const float* ia_w2     = (const float*)d_in[10];
    const float* ia_b2     = (const float*)d_in[11];
    const float* ca_W1     = (const float*)d_in[12];
    const float* ca_b1     = (const float*)d_in[13];
    const float* ca_w2     = (const float*)d_in[14];
    const float* ca_b2     = (const float*)d_in[15];
    const float* hg        = (const float*)d_in[16];
    const float* hb        = (const float*)d_in[17];
    const float* hm        = (const float*)d_in[18];
    const float* hv        = (const float*)d_in[19];
    const float* head_W    = (const float*)d_in[20];
    const float* head_b    = (const float*)d_in[21];

    char* ws = (char*)d_ws;
    unsigned short* emb16 = (unsigned short*)ws;                       // 8 MB
    unsigned short* g16   = (unsigned short*)(ws + ((size_t)8 << 20)); // 8 MB (reused as part)
    unsigned short* BtE   = (unsigned short*)(ws + ((size_t)16 << 20));          // 512 KB
    unsigned short* BtI   = (unsigned short*)(ws + ((size_t)17 << 20));          // 128 KB
    float* soft_t = (float*)(ws + ((size_t)18 << 20));                 // [B,K,N]
    float* s_t    = soft_t + (size_t)B * K * N;
    float* as_t   = s_t    + (size_t)B * K * N;
    float* cl     = as_t   + (size_t)B * K * N;
    float* sck    = cl     + (size_t)B * K * Z;
    float* part   = (float*)g16;   // 5.25 MB, g16 dead after inst4_kernel

    presplit2_kernel<<<((F + Z) * 256) / 256, 256, 0, stream>>>(enc_W, BtE, ia_W1, BtI);

    int nblk = ((B * N) / 64) * (Z / 64);   // 1024
    gemm5_kernel<1, 0><<<nblk, 256, 0, stream>>>(bags, BtE, emb16, F,
                                                 enc_b, bn1_gamma, bn1_beta, bn1_mean, bn1_var);
    gemm5_kernel<0, 1><<<nblk, 256, 0, stream>>>(emb16, BtI, g16, Z,
                                                 nullptr, nullptr, nullptr, nullptr, nullptr);

    inst4_kernel<<<(B * N) / IPB4, 320, 0, stream>>>(emb16, g16, centroids, ia_b1, ia_w2, ia_b2,
                                                     soft_t, s_t);
    attn_kernel<<<B * K, 256, 0, stream>>>(s_t, soft_t, as_t);
    cl_part_kernel<<<B * CCH, 256, 0, stream>>>(as_t, emb16, part);
    clred_sck_kernel<<<B * K, 256, 0, stream>>>(part, cl, ca_W1, ca_b1, ca_w2, ca_b2, sck);
    head_fin_kernel<<<B, 256, 0, stream>>>(cl, sck, hg, hb, hm, hv, head_W, head_b,
                                           (float*)d_out);
}

// Round 21
// 108.107 us; speedup vs baseline: 1.0825x; 1.0201x over previous
//
#include <hip/hip_runtime.h>
#include <math.h>

#define B 8
#define N 2048
#define F 1024
#define Z 256
#define K 10
#define OUT 2
#define EPSV 1e-5f
#define CCH 64            // cl chunks per bag
#define CHN (N / CCH)     // 32 instances per chunk
#define IPB4 16           // instances per inst4 block

typedef __attribute__((ext_vector_type(8))) short bf16x8;
typedef __attribute__((ext_vector_type(8))) unsigned short u16x8;
typedef __attribute__((ext_vector_type(4))) float f32x4;

__device__ __forceinline__ float fast_tanh(float x) {
    float t = __expf(2.0f * x);
    return 1.0f - 2.0f / (t + 1.0f);
}
__device__ __forceinline__ unsigned short f2bf_rne(float x) {
    unsigned int u = __float_as_uint(x);
    unsigned int r = (u + 0x7FFFu + ((u >> 16) & 1u)) >> 16;
    return (unsigned short)r;
}
__device__ __forceinline__ float bf2f(unsigned short h) {
    return __uint_as_float(((unsigned int)h) << 16);
}
__device__ __forceinline__ unsigned int pack2(unsigned short a, unsigned short b) {
    return (unsigned)a | ((unsigned)b << 16);
}

__device__ __forceinline__ float wave_sum(float v) {
    #pragma unroll
    for (int off = 32; off > 0; off >>= 1) v += __shfl_xor(v, off, 64);
    return v;
}
__device__ __forceinline__ float block_sum(float v, float* red) {
    int lane = threadIdx.x & 63, wave = threadIdx.x >> 6;
    v = wave_sum(v);
    __syncthreads();
    if (lane == 0) red[wave] = v;
    __syncthreads();
    return red[0] + red[1] + red[2] + red[3];
}

// ---- presplit both weights: W [Kd][256] fp32 -> Bt [256][Kd] bf16 (XOR swz) ----
__global__ __launch_bounds__(256)
void presplit2_kernel(const float* __restrict__ We, unsigned short* __restrict__ BtE,
                      const float* __restrict__ Wi, unsigned short* __restrict__ BtI)
{
    int tt = blockIdx.x * 256 + threadIdx.x;
    const float* W;
    unsigned short* Bt;
    int Kd, idx;
    if (tt < F * 256) { W = We; Bt = BtE; Kd = F; idx = tt; }
    else              { W = Wi; Bt = BtI; Kd = Z; idx = tt - F * 256; }
    int c = idx & 255;
    int k = idx >> 8;
    unsigned short h = f2bf_rne(W[(size_t)k * 256 + c]);
    int seg = k & ~63;
    int g = (k >> 3) & 7;
    int gs = g ^ (c & 7);
    Bt[(size_t)c * Kd + seg + gs * 8 + (k & 7)] = h;
}

// ---- gemm5 (r13 exact): 64x64 tile, 4 waves, acc[2][2], BK=64, dbuf, 2-phase ----
template<int EPI, int ABF16>
__global__ __launch_bounds__(256, 4)
void gemm5_kernel(const void* __restrict__ Ap,
                  const unsigned short* __restrict__ Bt,
                  unsigned short* __restrict__ Cout, int Kd,
                  const float* __restrict__ bias,
                  const float* __restrict__ gamma, const float* __restrict__ beta,
                  const float* __restrict__ mean, const float* __restrict__ var)
{
    const int Nd = 256;
    __shared__ unsigned short A_s[2][64 * 64];   // 16 KB
    __shared__ unsigned short B_s[2][64 * 64];   // 16 KB

    int t = threadIdx.x;
    int l = t & 63, w = t >> 6;
    int wr = w >> 1, wc = w & 1;
    int lr = l & 15, lq = l >> 4;

    int nwg = gridDim.x;
    int bid = blockIdx.x;
    int lwg = (bid & 7) * (nwg >> 3) + (bid >> 3);
    int m0 = (lwg >> 2) * 64;
    int cb = (lwg & 3) * 64;

    int arow = t >> 2, aq = t & 3;

    f32x4 acc[2][2];
    #pragma unroll
    for (int i = 0; i < 2; ++i)
        #pragma unroll
        for (int j = 0; j < 2; ++j) acc[i][j] = (f32x4)0.0f;

    const float* Af = (const float*)Ap;
    const unsigned short* Ab = (const unsigned short*)Ap;
    float4 areg[4];

    auto stageB = [&](int k0, int buf) {
        #pragma unroll
        for (int i = 0; i < 2; ++i) {
            int c0 = i * 256 + w * 64;
            int cc = c0 + l;
            int row = cc >> 3, gr = cc & 7;
            size_t src = (size_t)(cb + row) * Kd + k0 + gr * 8;
            __builtin_amdgcn_global_load_lds(
                (const __attribute__((address_space(1))) void*)(Bt + src),
                (__attribute__((address_space(3))) void*)((char*)&B_s[buf][0] + (size_t)cc * 16),
                16, 0, 0);
        }
    };
    auto stageA16 = [&](int k0, int buf) {
        #pragma unroll
        for (int i = 0; i < 2; ++i) {
            int c0 = i * 256 + w * 64;
            int cc = c0 + l;
            int row = cc >> 3, gr = cc & 7;
            size_t src = (size_t)(m0 + row) * Kd + k0 + ((gr ^ (row & 7)) << 3);
            __builtin_amdgcn_global_load_lds(
                (const __attribute__((address_space(1))) void*)(Ab + src),
                (__attribute__((address_space(3))) void*)((char*)&A_s[buf][0] + (size_t)cc * 16),
                16, 0, 0);
        }
    };
    auto loadA = [&](int k0) {
        #pragma unroll
        for (int q = 0; q < 4; ++q)
            areg[q] = *(const float4*)&Af[(size_t)(m0 + arow) * Kd + k0 + aq * 16 + q * 4];
    };
    auto writeA = [&](int buf) {
        #pragma unroll
        for (int j = 0; j < 2; ++j) {
            int g = aq * 2 + j;
            float4 v0 = areg[2 * j], v1 = areg[2 * j + 1];
            uint4 hv;
            hv.x = pack2(f2bf_rne(v0.x), f2bf_rne(v0.y));
            hv.y = pack2(f2bf_rne(v0.z), f2bf_rne(v0.w));
            hv.z = pack2(f2bf_rne(v1.x), f2bf_rne(v1.y));
            hv.w = pack2(f2bf_rne(v1.z), f2bf_rne(v1.w));
            *(uint4*)((char*)&A_s[buf][0] + arow * 128 + ((g ^ (arow & 7)) << 4)) = hv;
        }
    };

    int NK = Kd >> 6;
    if (ABF16) stageA16(0, 0);
    else       loadA(0);
    stageB(0, 0);
    if (!ABF16) writeA(0);
    asm volatile("s_waitcnt vmcnt(0) lgkmcnt(0)" ::: "memory");
    __builtin_amdgcn_s_barrier();

    int cur = 0;
    for (int ks = 0; ks < NK; ++ks) {
        if (ks + 1 < NK) {
            int kn = (ks + 1) << 6;
            if (ABF16) stageA16(kn, cur ^ 1);
            else       loadA(kn);
            stageB(kn, cur ^ 1);
        }
        #pragma unroll
        for (int sub = 0; sub < 2; ++sub) {
            int g = sub * 4 + lq;
            bf16x8 ah[2], bh[2];
            #pragma unroll
            for (int f = 0; f < 2; ++f) {
                int ra = wr * 32 + f * 16 + lr;
                ah[f] = *(const bf16x8*)((const char*)&A_s[cur][0] + ra * 128 + ((g ^ (ra & 7)) << 4));
                int rb = wc * 32 + f * 16 + lr;
                bh[f] = *(const bf16x8*)((const char*)&B_s[cur][0] + rb * 128 + ((g ^ (rb & 7)) << 4));
            }
            #pragma unroll
            for (int mi = 0; mi < 2; ++mi)
                #pragma unroll
                for (int ni = 0; ni < 2; ++ni)
                    acc[mi][ni] = __builtin_amdgcn_mfma_f32_16x16x32_bf16(
                        ah[mi], bh[ni], acc[mi][ni], 0, 0, 0);
        }
        if (ks + 1 < NK) {
            if (!ABF16) writeA(cur ^ 1);
            asm volatile("s_waitcnt vmcnt(0) lgkmcnt(0)" ::: "memory");
            __builtin_amdgcn_s_barrier();
        }
        cur ^= 1;
    }

    #pragma unroll
    for (int ni = 0; ni < 2; ++ni) {
        int c = cb + wc * 32 + ni * 16 + lr;
        float bi = 0.f, sc = 1.f, sh = 0.f;
        if (EPI == 1) {
            bi = bias[c];
            float rs = rsqrtf(var[c] + EPSV) * gamma[c];
            sc = rs;
            sh = beta[c] - mean[c] * rs;
        }
        #pragma unroll
        for (int mi = 0; mi < 2; ++mi) {
            int rbase = m0 + wr * 32 + mi * 16 + lq * 4;
            #pragma unroll
            for (int j = 0; j < 4; ++j) {
                float x = acc[mi][ni][j];
                if (EPI == 1) {
                    x = fmaxf(x + bi, 0.0f);
                    x = x * sc + sh;
                }
                Cout[(size_t)(rbase + j) * Nd + c] = f2bf_rne(x);
            }
        }
    }
}

// ---- inst4 (r13 exact): thread = (instance, k, z-half). 320 thr / 16 inst. ----
__global__ __launch_bounds__(320)
void inst4_kernel(const unsigned short* __restrict__ emb16,
                  const unsigned short* __restrict__ g16,
                  const float* __restrict__ cent, const float* __restrict__ ia_b1,
                  const float* __restrict__ ia_w2, const float* __restrict__ ia_b2,
                  float* __restrict__ soft_t, float* __restrict__ s_t)
{
    __shared__ unsigned short eg[IPB4][280];
    __shared__ float cent_s[K][260];
    __shared__ float cn_s[K];
    __shared__ float b1_s[Z], w2_s[Z];
    __shared__ float part_d[IPB4][K][2];
    __shared__ float en2_s[IPB4][2];
    __shared__ float nd_s[IPB4][12];

    int t = threadIdx.x;
    int half = t / 160;
    int r = t - half * 160;
    int i = r / 10;
    int k = r - i * 10;
    int inst0 = blockIdx.x * IPB4;
    int b = inst0 >> 11;
    int n0 = inst0 & (N - 1);

    for (int idx = t; idx < (K * Z) / 4; idx += 320) {
        int row = idx >> 6, c4 = idx & 63;
        *(float4*)&cent_s[row][c4 * 4] = ((const float4*)cent)[idx];
    }
    if (t < Z) { b1_s[t] = ia_b1[t]; w2_s[t] = ia_w2[t]; }
    for (int idx = t; idx < IPB4 * 32; idx += 320) {
        int rr = idx >> 5, c = idx & 31;
        *(u16x8*)&eg[rr][c * 8] = *(const u16x8*)&emb16[(size_t)(inst0 + rr) * Z + c * 8];
    }
    __syncthreads();

    if (t < K) {
        float s = 0.0f;
        for (int z = 0; z < Z; ++z) s += cent_s[t][z] * cent_s[t][z];
        cn_s[t] = s;
    }
    __syncthreads();

    {
        float dot = 0.0f, en2 = 0.0f;
        int zb = half * 16;
        #pragma unroll 4
        for (int zc = 0; zc < 16; ++zc) {
            int z8 = (zb + zc) * 8;
            u16x8 e8 = *(const u16x8*)&eg[i][z8];
            float4 ca = *(const float4*)&cent_s[k][z8];
            float4 cbv = *(const float4*)&cent_s[k][z8 + 4];
            float ev[8];
            #pragma unroll
            for (int j = 0; j < 8; ++j) ev[j] = bf2f((unsigned short)e8[j]);
            dot = fmaf(ev[0], ca.x, dot);  dot = fmaf(ev[1], ca.y, dot);
            dot = fmaf(ev[2], ca.z, dot);  dot = fmaf(ev[3], ca.w, dot);
            dot = fmaf(ev[4], cbv.x, dot); dot = fmaf(ev[5], cbv.y, dot);
            dot = fmaf(ev[6], cbv.z, dot); dot = fmaf(ev[7], cbv.w, dot);
            #pragma unroll
            for (int j = 0; j < 8; ++j) en2 = fmaf(ev[j], ev[j], en2);
        }
        part_d[i][k][half] = dot;
        if (k == 0) en2_s[i][half] = en2;
    }
    __syncthreads();

    if (half == 0) {
        float dsum = part_d[i][k][0] + part_d[i][k][1];
        float e2 = en2_s[i][0] + en2_s[i][1];
        float d2 = e2 + cn_s[k] - 2.0f * dsum;
        nd_s[i][k] = -sqrtf(fmaxf(d2, 0.0f));
    }
    __syncthreads();

    float mx = nd_s[i][0];
    #pragma unroll
    for (int kk = 1; kk < K; ++kk) mx = fmaxf(mx, nd_s[i][kk]);
    float se = 0.0f;
    #pragma unroll
    for (int kk = 0; kk < K; ++kk) se += __expf(nd_s[i][kk] - mx);
    float sm = __expf(nd_s[i][k] - mx) / se;
    if (half == 0) soft_t[((size_t)b * K + k) * N + n0 + i] = sm;
    __syncthreads();

    for (int idx = t; idx < IPB4 * 32; idx += 320) {
        int rr = idx >> 5, c = idx & 31;
        *(u16x8*)&eg[rr][c * 8] = *(const u16x8*)&g16[(size_t)(inst0 + rr) * Z + c * 8];
    }
    __syncthreads();

    {
        float acc = 0.0f;
        int zb = half * 16;
        #pragma unroll 2
        for (int zc = 0; zc < 16; ++zc) {
            int z8 = (zb + zc) * 8;
            u16x8 g8 = *(const u16x8*)&eg[i][z8];
            float4 b1a = *(const float4*)&b1_s[z8];
            float4 b1b = *(const float4*)&b1_s[z8 + 4];
            float4 w2a = *(const float4*)&w2_s[z8];
            float4 w2b = *(const float4*)&w2_s[z8 + 4];
            float gv[8];
            #pragma unroll
            for (int j = 0; j < 8; ++j) gv[j] = bf2f((unsigned short)g8[j]);
            acc = fmaf(w2a.x, fast_tanh(fmaf(sm, gv[0], b1a.x)), acc);
            acc = fmaf(w2a.y, fast_tanh(fmaf(sm, gv[1], b1a.y)), acc);
            acc = fmaf(w2a.z, fast_tanh(fmaf(sm, gv[2], b1a.z)), acc);
            acc = fmaf(w2a.w, fast_tanh(fmaf(sm, gv[3], b1a.w)), acc);
            acc = fmaf(w2b.x, fast_tanh(fmaf(sm, gv[4], b1b.x)), acc);
            acc = fmaf(w2b.y, fast_tanh(fmaf(sm, gv[5], b1b.y)), acc);
            acc = fmaf(w2b.z, fast_tanh(fmaf(sm, gv[6], b1b.z)), acc);
            acc = fmaf(w2b.w, fast_tanh(fmaf(sm, gv[7], b1b.w)), acc);
        }
        part_d[i][k][half] = acc;
    }
    __syncthreads();

    if (half == 0) {
        float s = part_d[i][k][0] + part_d[i][k][1] + ia_b2[0];
        s_t[((size_t)b * K + k) * N + n0 + i] = s;
    }
}

// ---- cl partials with deferred softmax: P_c[k][z] = sum_n e_n*soft_n*emb_nz,
//      D_c[k] = sum_n e_n, where e_n = exp(s_n) (no max needed: |s| <= ~18). ----
__global__ __launch_bounds__(256)
void cl_part_kernel(const float* __restrict__ s_t, const float* __restrict__ soft_t,
                    const unsigned short* __restrict__ emb16,
                    float* __restrict__ part, float* __restrict__ part2)
{
    __shared__ float sas[K][CHN];
    __shared__ float ses[K][CHN];
    int b = blockIdx.x / CCH, c = blockIdx.x % CCH;
    int z = threadIdx.x;
    int n0 = c * CHN;
    for (int i = threadIdx.x; i < K * CHN; i += 256) {
        int k = i / CHN, n = i % CHN;
        size_t off = ((size_t)b * K + k) * N + n0 + n;
        float e = __expf(s_t[off]);
        ses[k][n] = e;
        sas[k][n] = e * soft_t[off];
    }
    __syncthreads();
    if (threadIdx.x < K) {
        float d = 0.0f;
        #pragma unroll
        for (int n = 0; n < CHN; ++n) d += ses[threadIdx.x][n];
        part2[((size_t)b * CCH + c) * K + threadIdx.x] = d;
    }
    float acc[K] = {};
    #pragma unroll 4
    for (int j = 0; j < CHN; ++j) {
        float e = bf2f(emb16[((size_t)b * N + n0 + j) * Z + z]);
        #pragma unroll
        for (int k = 0; k < K; ++k) acc[k] = fmaf(sas[k][j], e, acc[k]);
    }
    #pragma unroll
    for (int k = 0; k < K; ++k)
        part[(((size_t)b * CCH + c) * K + k) * Z + z] = acc[k];
}

// ---- fused: cl reduce (P/D) over chunks + cluster-attn score sck[b,k] ----
__global__ __launch_bounds__(256)
void clred_sck_kernel(const float* __restrict__ part, const float* __restrict__ part2,
                      float* __restrict__ cl,
                      const float* __restrict__ ca_W1, const float* __restrict__ ca_b1,
                      const float* __restrict__ ca_w2, const float* __restrict__ ca_b2,
                      float* __restrict__ sck)
{
    __shared__ float scl[Z];
    __shared__ float red[4];
    int bk = blockIdx.x;
    int b = bk / K, k = bk % K;
    int t = threadIdx.x;
    float s = 0.0f, D = 0.0f;
    #pragma unroll 8
    for (int c = 0; c < CCH; ++c) {
        s += part[(((size_t)b * CCH + c) * K + k) * Z + t];
        D += part2[((size_t)b * CCH + c) * K + k];
    }
    s = s / D;
    cl[(size_t)bk * Z + t] = s;
    scl[t] = s;
    __syncthreads();
    float acc = 0.0f;
    #pragma unroll 8
    for (int z = 0; z < Z; ++z)
        acc = fmaf(scl[z], ca_W1[(size_t)z * Z + t], acc);
    float h = fast_tanh(acc + ca_b1[t]);
    float v = block_sum(h * ca_w2[t], red);
    if (t == 0) sck[bk] = v + ca_b2[0];
}

__global__ __launch_bounds__(256)
void head_fin_kernel(const float* __restrict__ cl, const float* __restrict__ sck,
                     const float* __restrict__ hg, const float* __restrict__ hb,
                     const float* __restrict__ hm, const float* __restrict__ hv,
                     const float* __restrict__ head_W, const float* __restrict__ head_b,
                     float* __restrict__ outp)
{
    __shared__ float red[4];
    __shared__ float sks[K];
    int b = blockIdx.x, t = threadIdx.x;
    if (t < K) sks[t] = sck[b * K + t];
    __syncthreads();
    float mx = sks[0];
    #pragma unroll
    for (int k = 1; k < K; ++k) mx = fmaxf(mx, sks[k]);
    float e[K], se = 0.0f;
    #pragma unroll
    for (int k = 0; k < K; ++k) { e[k] = __expf(sks[k] - mx); se += e[k]; }
    float inv = 1.0f / se;
    float pooled = 0.0f;
    #pragma unroll
    for (int k = 0; k < K; ++k)
        pooled = fmaf(e[k] * inv, cl[((size_t)b * K + k) * Z + t], pooled);
    pooled = (pooled - hm[t]) * rsqrtf(hv[t] + EPSV) * hg[t] + hb[t];
    float p0 = block_sum(pooled * head_W[t * OUT + 0], red);
    __syncthreads();
    float p1 = block_sum(pooled * head_W[t * OUT + 1], red);
    if (t == 0) {
        outp[b * OUT + 0] = p0 + head_b[0];
        outp[b * OUT + 1] = p1 + head_b[1];
    }
}

extern "C" void kernel_launch(void* const* d_in, const int* in_sizes, int n_in,
                              void* d_out, int out_size, void* d_ws, size_t ws_size,
                              hipStream_t stream)
{
    const float* bags      = (const float*)d_in[0];
    const float* enc_W     = (const float*)d_in[1];
    const float* enc_b     = (const float*)d_in[2];
    const float* bn1_gamma = (const float*)d_in[3];
    const float* bn1_beta  = (const float*)d_in[4];
    const float* bn1_mean  = (const float*)d_in[5];
    const float* bn1_var   = (const float*)d_in[6];
    const float* centroids = (const float*)d_in[7];
    const float* ia_W1     = (const float*)d_in[8];
    const float* ia_b1     = (const float*)d_in[9];
    const float* ia_w2     = (const float*)d_in[10];
    const float* ia_b2     = (const float*)d_in[11];
    const float* ca_W1     = (const float*)d_in[12];
    const float* ca_b1     = (const float*)d_in[13];
    const float* ca_w2     = (const float*)d_in[14];
    const float* ca_b2     = (const float*)d_in[15];
    const float* hg        = (const float*)d_in[16];
    const float* hb        = (const float*)d_in[17];
    const float* hm        = (const float*)d_in[18];
    const float* hv        = (const float*)d_in[19];
    const float* head_W    = (const float*)d_in[20];
    const float* head_b    = (const float*)d_in[21];

    char* ws = (char*)d_ws;
    unsigned short* emb16 = (unsigned short*)ws;                       // 8 MB
    unsigned short* g16   = (unsigned short*)(ws + ((size_t)8 << 20)); // 8 MB (reused as part)
    unsigned short* BtE   = (unsigned short*)(ws + ((size_t)16 << 20));          // 512 KB
    unsigned short* BtI   = (unsigned short*)(ws + ((size_t)17 << 20));          // 128 KB
    float* soft_t = (float*)(ws + ((size_t)18 << 20));                 // [B,K,N]
    float* s_t    = soft_t + (size_t)B * K * N;
    float* cl     = s_t    + (size_t)B * K * N;
    float* sck    = cl     + (size_t)B * K * Z;
    float* part   = (float*)g16;                   // 5.25 MB, g16 dead after inst4
    float* part2  = part + (size_t)B * CCH * K * Z; // 20 KB, fits in the 8 MB region

    presplit2_kernel<<<((F + Z) * 256) / 256, 256, 0, stream>>>(enc_W, BtE, ia_W1, BtI);

    int nblk = ((B * N) / 64) * (Z / 64);   // 1024
    gemm5_kernel<1, 0><<<nblk, 256, 0, stream>>>(bags, BtE, emb16, F,
                                                 enc_b, bn1_gamma, bn1_beta, bn1_mean, bn1_var);
    gemm5_kernel<0, 1><<<nblk, 256, 0, stream>>>(emb16, BtI, g16, Z,
                                                 nullptr, nullptr, nullptr, nullptr, nullptr);

    inst4_kernel<<<(B * N) / IPB4, 320, 0, stream>>>(emb16, g16, centroids, ia_b1, ia_w2, ia_b2,
                                                     soft_t, s_t);
    cl_part_kernel<<<B * CCH, 256, 0, stream>>>(s_t, soft_t, emb16, part, part2);
    clred_sck_kernel<<<B * K, 256, 0, stream>>>(part, part2, cl, ca_W1, ca_b1, ca_w2, ca_b2, sck);
    head_fin_kernel<<<B, 256, 0, stream>>>(cl, sck, hg, hb, hm, hv, head_W, head_b,
                                           (float*)d_out);
}